// Round 1
// baseline (2147.011 us; speedup 1.0000x reference)
//
#include <hip/hip_runtime.h>

// 2-layer LSTM encoder, B=128, T=1024, F=1, HID=128, EMB=64.
// One workgroup (512 threads) per batch element; weights register-resident as
// f16 pairs; recurrent matmuls via v_dot2_f32_f16 with fp32 accumulate;
// h broadcast via one stride-1 LDS read + v_readlane (SGPR operand).

#define TB   1024
#define HID1 128
#define G1   512      // 4*HID1
#define EMB2 64
#define G2   256      // 4*EMB2

typedef _Float16 h2v __attribute__((ext_vector_type(2)));

#if __has_builtin(__builtin_amdgcn_fdot2)
#define FDOT2(a,b,c) __builtin_amdgcn_fdot2((a),(b),(c),false)
#else
static __device__ __forceinline__ float FDOT2(h2v a, h2v b, float c){
  return (float)a.x*(float)b.x + ((float)a.y*(float)b.y + c);
}
#endif

static __device__ __forceinline__ float fast_exp2(float x){
#if __has_builtin(__builtin_amdgcn_exp2f)
  return __builtin_amdgcn_exp2f(x);
#else
  return __exp2f(x);
#endif
}
static __device__ __forceinline__ float fast_rcp(float x){
#if __has_builtin(__builtin_amdgcn_rcpf)
  return __builtin_amdgcn_rcpf(x);
#else
  return 1.0f / x;
#endif
}
static __device__ __forceinline__ float sigmoid_f(float x){
  // 1/(1+e^-x) = 1/(1+2^(-x*log2e))
  return fast_rcp(1.0f + fast_exp2(-1.44269504088896340736f * x));
}
static __device__ __forceinline__ float tanh_f(float x){
  // tanh(x) = 1 - 2/(1+e^{2x});  saturates correctly at +-inf
  return 1.0f - 2.0f * fast_rcp(1.0f + fast_exp2(2.88539008177792681472f * x));
}

static __device__ __forceinline__ h2v bc(int v){
  return __builtin_bit_cast(h2v, v);
}

#define RL(v,l) __builtin_amdgcn_readlane((v),(l))

__launch_bounds__(512, 1)
__global__ void lstm2_kernel(const float* __restrict__ x,
                             const float* __restrict__ w_ih1,
                             const float* __restrict__ w_hh1,
                             const float* __restrict__ b_ih1,
                             const float* __restrict__ b_hh1,
                             const float* __restrict__ w_ih2,
                             const float* __restrict__ w_hh2,
                             const float* __restrict__ b_ih2,
                             const float* __restrict__ b_hh2,
                             float* __restrict__ out)
{
  __shared__ float    xs[TB];
  __shared__ float    gates1[G1];
  __shared__ float    part2[G2 * 2];
  __shared__ unsigned h1u[HID1 / 2];   // h1 as 64 f16-pairs
  __shared__ unsigned h2u[EMB2 / 2];   // h2 as 32 f16-pairs

  const int t    = threadIdx.x;   // 0..511
  const int b    = blockIdx.x;    // 0..127
  const int lane = t & 63;
  const int wv   = t >> 6;        // wave 0..7
  const int kh   = t >> 8;        // 0 for waves 0-3, 1 for waves 4-7 (wave-uniform)
  const int r2   = t & 255;       // layer-2 gate row

  // ---- weights -> registers as f16 pairs ----
  // L1: thread t owns gate row t of w_hh1 (128 weights = 64 pairs)
  h2v w1[64];
  {
    const float2* src = (const float2*)(w_hh1 + t * HID1);
    #pragma unroll
    for (int p = 0; p < 64; ++p){
      float2 v = src[p];
      h2v w; w.x = (_Float16)v.x; w.y = (_Float16)v.y; w1[p] = w;
    }
  }
  // L2: thread t owns row r2, k-half kh of w_ih2 (64 weights = 32 pairs)
  h2v wi2[32];
  {
    const float2* src = (const float2*)(w_ih2 + r2 * HID1 + kh * 64);
    #pragma unroll
    for (int p = 0; p < 32; ++p){
      float2 v = src[p];
      h2v w; w.x = (_Float16)v.x; w.y = (_Float16)v.y; wi2[p] = w;
    }
  }
  // L2: row r2, k-half kh of w_hh2 (32 weights = 16 pairs)
  h2v wh2[16];
  {
    const float2* src = (const float2*)(w_hh2 + r2 * EMB2 + kh * 32);
    #pragma unroll
    for (int p = 0; p < 16; ++p){
      float2 v = src[p];
      h2v w; w.x = (_Float16)v.x; w.y = (_Float16)v.y; wh2[p] = w;
    }
  }
  const float bias1 = b_ih1[t] + b_hh1[t];
  const float wx1   = w_ih1[t];                       // w_ih1 is (512,1)
  const float bias2 = (kh == 0) ? (b_ih2[r2] + b_hh2[r2]) : 0.0f;

  // ---- x preload + state init ----
  xs[t]       = x[b * TB + t];
  xs[t + 512] = x[b * TB + t + 512];
  if (t < HID1/2)                h1u[t]      = 0u;
  if (t >= 64 && t < 64+EMB2/2)  h2u[t - 64] = 0u;
  __syncthreads();

  float c1 = 0.0f, c2 = 0.0f;
  const int  jj     = wv + 8 * lane;   // ew cell index (valid when lane small)
  const bool do_ew1 = (lane < 16);     // 128 cells over 8 waves x 16 lanes
  const bool do_ew2 = (lane < 8);      // 64 cells over 8 waves x 8 lanes

  #pragma unroll 1
  for (int st = 0; st < TB; ++st){
    // ---------- phase 1: layer-1 gates (gate g = t) ----------
    int vh1 = (int)h1u[lane];          // lane p holds h1 pair p
    float accA = __builtin_fmaf(xs[st], wx1, bias1);
    float accB = 0.0f, accC = 0.0f, accD = 0.0f;
    #pragma unroll
    for (int p = 0; p < 16; ++p){
      accA = FDOT2(w1[4*p+0], bc(RL(vh1, 4*p+0)), accA);
      accB = FDOT2(w1[4*p+1], bc(RL(vh1, 4*p+1)), accB);
      accC = FDOT2(w1[4*p+2], bc(RL(vh1, 4*p+2)), accC);
      accD = FDOT2(w1[4*p+3], bc(RL(vh1, 4*p+3)), accD);
    }
    gates1[t] = (accA + accB) + (accC + accD);
    __syncthreads();

    // ---------- phase 2: layer-1 elementwise (cell jj) ----------
    if (do_ew1){
      float gi = gates1[jj];
      float gf = gates1[jj + 128];
      float gg = gates1[jj + 256];
      float go = gates1[jj + 384];
      c1 = sigmoid_f(gf) * c1 + sigmoid_f(gi) * tanh_f(gg);
      float h = sigmoid_f(go) * tanh_f(c1);
      ((_Float16*)h1u)[jj] = (_Float16)h;
    }
    __syncthreads();

    // ---------- phase 3: layer-2 gates (row r2, half kh) ----------
    int vh1n = (int)h1u[lane];
    int vh2  = (int)h2u[lane & 31];
    float a2A = bias2, a2B = 0.0f;
    #pragma unroll
    for (int p = 0; p < 16; ++p){
      a2A = FDOT2(wi2[2*p+0], bc(RL(vh1n, kh*32 + 2*p+0)), a2A);
      a2B = FDOT2(wi2[2*p+1], bc(RL(vh1n, kh*32 + 2*p+1)), a2B);
    }
    #pragma unroll
    for (int p = 0; p < 8; ++p){
      a2A = FDOT2(wh2[2*p+0], bc(RL(vh2, kh*16 + 2*p+0)), a2A);
      a2B = FDOT2(wh2[2*p+1], bc(RL(vh2, kh*16 + 2*p+1)), a2B);
    }
    part2[2*r2 + kh] = a2A + a2B;
    __syncthreads();

    // ---------- phase 4: layer-2 elementwise (cell jj, lane<8) ----------
    if (do_ew2){
      float2 pi = ((float2*)part2)[jj];
      float2 pf = ((float2*)part2)[jj + 64];
      float2 pg = ((float2*)part2)[jj + 128];
      float2 po = ((float2*)part2)[jj + 192];
      float gi = pi.x + pi.y;
      float gf = pf.x + pf.y;
      float gg = pg.x + pg.y;
      float go = po.x + po.y;
      c2 = sigmoid_f(gf) * c2 + sigmoid_f(gi) * tanh_f(gg);
      float h = sigmoid_f(go) * tanh_f(c2);
      ((_Float16*)h2u)[jj] = (_Float16)h;
      if (st == TB - 1) out[b * EMB2 + jj] = h;   // fp32 result, last step
    }
    __syncthreads();
  }
}

extern "C" void kernel_launch(void* const* d_in, const int* in_sizes, int n_in,
                              void* d_out, int out_size, void* d_ws, size_t ws_size,
                              hipStream_t stream) {
  lstm2_kernel<<<dim3(128), dim3(512), 0, stream>>>(
      (const float*)d_in[0],   // x
      (const float*)d_in[1],   // w_ih1
      (const float*)d_in[2],   // w_hh1
      (const float*)d_in[3],   // b_ih1
      (const float*)d_in[4],   // b_hh1
      (const float*)d_in[5],   // w_ih2
      (const float*)d_in[6],   // w_hh2
      (const float*)d_in[7],   // b_ih2
      (const float*)d_in[8],   // b_hh2
      (float*)d_out);
}

// Round 2
// 1400.303 us; speedup vs baseline: 1.5332x; 1.5332x over previous
//
#include <hip/hip_runtime.h>

// 2-layer LSTM encoder, B=128, T=1024, F=1, HID=128, EMB=64.
// One WG (512 thr) per batch element. Weights register-resident (f16 pairs),
// dots via v_dot2_f32_f16. ONE barrier per step: phase A (layer 1) -> barrier
// -> phase B (layer 2), h1/h2 double-buffered in LDS, gate->cell transposes
// done wave-locally with __shfl (no LDS gate arrays, no bank conflicts).

#define TB   1024
#define HID1 128
#define EMB2 64

typedef _Float16 h2v __attribute__((ext_vector_type(2)));
typedef _Float16 h8v __attribute__((ext_vector_type(8)));

#if __has_builtin(__builtin_amdgcn_fdot2)
#define FDOT2(a,b,c) __builtin_amdgcn_fdot2((a),(b),(c),false)
#else
static __device__ __forceinline__ float FDOT2(h2v a, h2v b, float c){
  return (float)a.x*(float)b.x + ((float)a.y*(float)b.y + c);
}
#endif

static __device__ __forceinline__ float fast_exp2(float x){
#if __has_builtin(__builtin_amdgcn_exp2f)
  return __builtin_amdgcn_exp2f(x);
#else
  return __exp2f(x);
#endif
}
static __device__ __forceinline__ float fast_rcp(float x){
#if __has_builtin(__builtin_amdgcn_rcpf)
  return __builtin_amdgcn_rcpf(x);
#else
  return 1.0f / x;
#endif
}
static __device__ __forceinline__ float sigmoid_f(float x){
  return fast_rcp(1.0f + fast_exp2(-1.44269504088896340736f * x));
}
static __device__ __forceinline__ float tanh_f(float x){
  return 1.0f - 2.0f * fast_rcp(1.0f + fast_exp2(2.88539008177792681472f * x));
}
static __device__ __forceinline__ h2v bc(int v){
  return __builtin_bit_cast(h2v, v);
}
#define RL(v,l) __builtin_amdgcn_readlane((v),(l))

__launch_bounds__(512, 2)
__global__ void lstm2_kernel(const float* __restrict__ x,
                             const float* __restrict__ w_ih1,
                             const float* __restrict__ w_hh1,
                             const float* __restrict__ b_ih1,
                             const float* __restrict__ b_hh1,
                             const float* __restrict__ w_ih2,
                             const float* __restrict__ w_hh2,
                             const float* __restrict__ b_ih2,
                             const float* __restrict__ b_hh2,
                             float* __restrict__ out)
{
  __shared__ __align__(16) float    xs[TB];
  __shared__ __align__(16) unsigned H1[2][HID1/2];  // h1 as f16 pairs, ping-pong
  __shared__ __align__(16) unsigned H2[2][EMB2/2];  // h2 as f16 pairs, ping-pong

  const int t = threadIdx.x;   // 0..511
  const int b = blockIdx.x;    // 0..127
  const int l = t & 63;        // lane
  const int w = t >> 6;        // wave 0..7

  // ---- phase-A assignment: wave w owns L1 cells [16w,16w+16) ----
  const int cA   = 16 * w + (l & 15);   // cell 0..127
  const int gA   = l >> 4;              // gate 0..3 (i,f,g,o)
  const int rowA = gA * HID1 + cA;      // row in w_hh1 (512 rows)

  // ---- phase-B assignment: wave w owns L2 cells [8w,8w+8) ----
  const int cB   = 8 * w + (l & 7);     // cell 0..63
  const int gB   = (l >> 3) & 3;        // gate 0..3
  const int kh   = l >> 5;              // k-half 0/1
  const int rowB = gB * EMB2 + cB;      // row in w_ih2/w_hh2 (256 rows)

  // ---- weights -> registers as f16 pairs ----
  h2v w1[64];                                  // w_hh1 row (128 wts)
  {
    const float2* src = (const float2*)(w_hh1 + rowA * HID1);
    #pragma unroll
    for (int p = 0; p < 64; ++p){
      float2 v = src[p];
      h2v q; q.x = (_Float16)v.x; q.y = (_Float16)v.y; w1[p] = q;
    }
  }
  h2v wi2[32];                                 // w_ih2 row, k-half (64 wts)
  {
    const float2* src = (const float2*)(w_ih2 + rowB * HID1 + kh * 64);
    #pragma unroll
    for (int p = 0; p < 32; ++p){
      float2 v = src[p];
      h2v q; q.x = (_Float16)v.x; q.y = (_Float16)v.y; wi2[p] = q;
    }
  }
  h2v wh2[16];                                 // w_hh2 row, k-half (32 wts)
  {
    const float2* src = (const float2*)(w_hh2 + rowB * EMB2 + kh * 32);
    #pragma unroll
    for (int p = 0; p < 16; ++p){
      float2 v = src[p];
      h2v q; q.x = (_Float16)v.x; q.y = (_Float16)v.y; wh2[p] = q;
    }
  }
  const float bias1 = b_ih1[rowA] + b_hh1[rowA];
  const float wx1   = w_ih1[rowA];                    // w_ih1 is (512,1)
  const float bias2 = (kh == 0) ? (b_ih2[rowB] + b_hh2[rowB]) : 0.0f;

  // ---- x preload + state init ----
  xs[t]       = x[b * TB + t];
  xs[t + 512] = x[b * TB + t + 512];
  if (t < 64)            { H1[0][t] = 0u; H1[1][t] = 0u; }
  else if (t < 96)       { H2[0][t-64] = 0u; H2[1][t-64] = 0u; }
  __syncthreads();

  float c1 = 0.0f, c2 = 0.0f;

  #pragma unroll 1
  for (int st = 0; st < TB; ++st){
    const int ra = st & 1;        // read buffer (prev step's h)
    const int wa = ra ^ 1;        // write buffer (this step's h)

    // ========== phase A: layer-1 gates + elementwise (wave-local) ==========
    int vh1 = (int)H1[ra][l];     // lane p holds h1 pair p (stride-1, no conflict)
    float accA = __builtin_fmaf(xs[st], wx1, bias1);
    float accB = 0.0f, accC = 0.0f, accD = 0.0f;
    #pragma unroll
    for (int p = 0; p < 16; ++p){
      accA = FDOT2(w1[4*p+0], bc(RL(vh1, 4*p+0)), accA);
      accB = FDOT2(w1[4*p+1], bc(RL(vh1, 4*p+1)), accB);
      accC = FDOT2(w1[4*p+2], bc(RL(vh1, 4*p+2)), accC);
      accD = FDOT2(w1[4*p+3], bc(RL(vh1, 4*p+3)), accD);
    }
    float acc = (accA + accB) + (accC + accD);

    // wave-local transpose: lane s<16 gathers the 4 gates of cell 16w+s
    const int s = l & 15;
    float gi = __shfl(acc, s);
    float gf = __shfl(acc, s + 16);
    float gg = __shfl(acc, s + 32);
    float go = __shfl(acc, s + 48);
    if (l < 16){
      c1 = sigmoid_f(gf) * c1 + sigmoid_f(gi) * tanh_f(gg);
      float h = sigmoid_f(go) * tanh_f(c1);
      ((_Float16*)&H1[wa][0])[cA] = (_Float16)h;   // cA == 16w+l here
    }
    __syncthreads();   // the ONLY barrier in the step

    // ========== phase B: layer-2 gates + elementwise (wave-local) ==========
    const h8v* pH1 = (const h8v*)&H1[wa][0];   // 16 chunks of 4 pairs
    const h8v* pH2 = (const h8v*)&H2[ra][0];   // 8 chunks
    float aA = (kh == 0) ? bias2 : 0.0f;
    float aB = 0.0f;
    #pragma unroll
    for (int i = 0; i < 8; ++i){               // w_ih2 . h1  (k-half)
      union { h8v v; h2v p[4]; } u;
      u.v = pH1[kh * 8 + i];                   // b128 broadcast (2 addrs/wave)
      aA = FDOT2(wi2[4*i+0], u.p[0], aA);
      aB = FDOT2(wi2[4*i+1], u.p[1], aB);
      aA = FDOT2(wi2[4*i+2], u.p[2], aA);
      aB = FDOT2(wi2[4*i+3], u.p[3], aB);
    }
    #pragma unroll
    for (int i = 0; i < 4; ++i){               // w_hh2 . h2  (k-half)
      union { h8v v; h2v p[4]; } u;
      u.v = pH2[kh * 4 + i];
      aA = FDOT2(wh2[4*i+0], u.p[0], aA);
      aB = FDOT2(wh2[4*i+1], u.p[1], aB);
      aA = FDOT2(wh2[4*i+2], u.p[2], aA);
      aB = FDOT2(wh2[4*i+3], u.p[3], aB);
    }
    float a2 = aA + aB;
    a2 += __shfl_xor(a2, 32);                  // combine k-halves

    const int s2 = l & 7;
    float g2i = __shfl(a2, s2);
    float g2f = __shfl(a2, s2 + 8);
    float g2g = __shfl(a2, s2 + 16);
    float g2o = __shfl(a2, s2 + 24);
    if (l < 8){
      c2 = sigmoid_f(g2f) * c2 + sigmoid_f(g2i) * tanh_f(g2g);
      float h = sigmoid_f(g2o) * tanh_f(c2);
      ((_Float16*)&H2[wa][0])[cB] = (_Float16)h;   // cB == 8w+l here
      if (st == TB - 1) out[b * EMB2 + cB] = h;
    }
    // no trailing barrier: B(t) -> A(t+1) hazards are covered by the
    // mid-step barrier of t and t+1 (double-buffered H1/H2; see analysis)
  }
}

extern "C" void kernel_launch(void* const* d_in, const int* in_sizes, int n_in,
                              void* d_out, int out_size, void* d_ws, size_t ws_size,
                              hipStream_t stream) {
  lstm2_kernel<<<dim3(128), dim3(512), 0, stream>>>(
      (const float*)d_in[0],   // x
      (const float*)d_in[1],   // w_ih1
      (const float*)d_in[2],   // w_hh1
      (const float*)d_in[3],   // b_ih1
      (const float*)d_in[4],   // b_hh1
      (const float*)d_in[5],   // w_ih2
      (const float*)d_in[6],   // w_hh2
      (const float*)d_in[7],   // b_ih2
      (const float*)d_in[8],   // b_hh2
      (float*)d_out);
}

// Round 3
// 841.034 us; speedup vs baseline: 2.5528x; 1.6650x over previous
//
#include <hip/hip_runtime.h>

// 2-layer LSTM encoder, B=128, T=1024, F=1, HID=128, EMB=64.
// One WG (512 thr) per batch element; recurrent matvecs on the MFMA pipe:
// v_mfma_f32_16x16x32_f16 with A = h broadcast across all 16 M-rows (LDS
// same-address b128 reads per quarter-wave). Weights register-resident as
// B-fragments (f16). Gate colocation: wave w owns N-tiles {w,w+8,w+16,w+24}
// (L1) / {w,w+4,w+8,w+12} (L2, waves 0-3) so i,f,g,o of each cell are in one
// lane's accumulators -> elementwise fully in-register. ONE barrier per step
// (ping-pong H1/H2; hazard analysis in session notes).

#define TB   1024
#define HID1 128
#define EMB2 64

typedef _Float16 f16x8 __attribute__((ext_vector_type(8)));
typedef float    f32x4 __attribute__((ext_vector_type(4)));

#define MFMA16(a,b,c) __builtin_amdgcn_mfma_f32_16x16x32_f16((a),(b),(c),0,0,0)

static __device__ __forceinline__ float fast_exp2(float x){
#if __has_builtin(__builtin_amdgcn_exp2f)
  return __builtin_amdgcn_exp2f(x);
#else
  return __exp2f(x);
#endif
}
static __device__ __forceinline__ float fast_rcp(float x){
#if __has_builtin(__builtin_amdgcn_rcpf)
  return __builtin_amdgcn_rcpf(x);
#else
  return 1.0f / x;
#endif
}
static __device__ __forceinline__ float sigmoid_f(float x){
  return fast_rcp(1.0f + fast_exp2(-1.44269504088896340736f * x));
}
static __device__ __forceinline__ float tanh_f(float x){
  return 1.0f - 2.0f * fast_rcp(1.0f + fast_exp2(2.88539008177792681472f * x));
}

// load 8 consecutive f32 -> f16x8 fragment
static __device__ __forceinline__ f16x8 load_frag(const float* p){
  f16x8 r;
  #pragma unroll
  for (int j = 0; j < 8; ++j) r[j] = (_Float16)p[j];
  return r;
}

__launch_bounds__(512, 2)
__global__ void lstm2_kernel(const float* __restrict__ x,
                             const float* __restrict__ w_ih1,
                             const float* __restrict__ w_hh1,
                             const float* __restrict__ b_ih1,
                             const float* __restrict__ b_hh1,
                             const float* __restrict__ w_ih2,
                             const float* __restrict__ w_hh2,
                             const float* __restrict__ b_ih2,
                             const float* __restrict__ b_hh2,
                             float* __restrict__ out)
{
  __shared__ __align__(16) float    xs[TB];
  __shared__ __align__(16) _Float16 H1[2][HID1];  // h1 ping-pong (single copy, broadcast rows)
  __shared__ __align__(16) _Float16 H2[2][EMB2];  // h2 ping-pong

  const int t    = threadIdx.x;   // 0..511
  const int b    = blockIdx.x;    // 0..127
  const int l    = t & 63;        // lane
  const int w    = t >> 6;        // wave 0..7
  const int col  = l & 15;        // N-index within tile (cell)
  const int quad = l >> 4;        // k-quad 0..3

  // ---- layer-1 weight B-fragments: wave w owns N-tiles {w,w+8,w+16,w+24} ----
  // gate g tile = w + 8g  ->  row nA = (w+8g)*16 + col;  K = 128 = 4 chunks
  f16x8 B1[4][4];
  float biasA[4], wxA[4];
  #pragma unroll
  for (int g = 0; g < 4; ++g){
    const int nA = (w + 8*g)*16 + col;
    biasA[g] = b_ih1[nA] + b_hh1[nA];
    wxA[g]   = w_ih1[nA];                       // w_ih1 is (512,1)
    #pragma unroll
    for (int k = 0; k < 4; ++k)
      B1[g][k] = load_frag(w_hh1 + nA*HID1 + k*32 + quad*8);
  }

  // ---- layer-2 weight B-fragments (waves 0-3): tiles {w,w+4,w+8,w+12} ----
  f16x8 B2i[4][4];   // w_ih2 part, K=128
  f16x8 B2h[4][2];   // w_hh2 part, K=64
  float biasB[4];
  if (w < 4){
    #pragma unroll
    for (int g = 0; g < 4; ++g){
      const int nB = (w + 4*g)*16 + col;
      biasB[g] = b_ih2[nB] + b_hh2[nB];
      #pragma unroll
      for (int k = 0; k < 4; ++k)
        B2i[g][k] = load_frag(w_ih2 + nB*HID1 + k*32 + quad*8);
      #pragma unroll
      for (int k = 0; k < 2; ++k)
        B2h[g][k] = load_frag(w_hh2 + nB*EMB2 + k*32 + quad*8);
    }
  }

  // ---- x preload + state init ----
  xs[t]       = x[b * TB + t];
  xs[t + 512] = x[b * TB + t + 512];
  if (t < HID1) { H1[0][t] = (_Float16)0.0f; H1[1][t] = (_Float16)0.0f; }
  else if (t < HID1 + EMB2){
    H2[0][t-HID1] = (_Float16)0.0f; H2[1][t-HID1] = (_Float16)0.0f;
  }
  __syncthreads();

  float c1 = 0.0f, c2 = 0.0f;
  const int cellA = 16*w + l;          // valid when l<16 (phase-A ew cell)
  const int cellB = 16*w + l;          // valid when w<4 && l<16

  #pragma unroll 1
  for (int st = 0; st < TB; ++st){
    const int cur = st & 1;            // h(st) buffer
    const int prv = cur ^ 1;           // h(st-1) buffer

    // ========== phase A: layer 1 ==========
    const float xt = xs[st];
    f32x4 acc[4];
    #pragma unroll
    for (int g = 0; g < 4; ++g){
      const float pre = __builtin_fmaf(xt, wxA[g], biasA[g]);
      acc[g] = (f32x4){pre, pre, pre, pre};
    }
    {
      const f16x8* pA = (const f16x8*)&H1[prv][0];   // 16 chunks of 8 f16
      #pragma unroll
      for (int k = 0; k < 4; ++k){
        f16x8 a = pA[4*k + quad];      // same addr per quarter-wave: broadcast
        #pragma unroll
        for (int g = 0; g < 4; ++g)
          acc[g] = MFMA16(a, B1[g][k], acc[g]);
      }
    }
    // rows of each C tile are identical (broadcast A) -> use reg 0
    if (l < 16){
      float gi = acc[0][0], gf = acc[1][0], gg = acc[2][0], go = acc[3][0];
      c1 = sigmoid_f(gf) * c1 + sigmoid_f(gi) * tanh_f(gg);
      float h = sigmoid_f(go) * tanh_f(c1);
      H1[cur][cellA] = (_Float16)h;
    }
    __syncthreads();   // the only barrier in the step

    // ========== phase B: layer 2 (waves 0-3) ==========
    if (w < 4){
      f32x4 acc2[4];
      #pragma unroll
      for (int g = 0; g < 4; ++g)
        acc2[g] = (f32x4){biasB[g], biasB[g], biasB[g], biasB[g]};
      const f16x8* pA1 = (const f16x8*)&H1[cur][0];
      #pragma unroll
      for (int k = 0; k < 4; ++k){
        f16x8 a = pA1[4*k + quad];
        #pragma unroll
        for (int g = 0; g < 4; ++g)
          acc2[g] = MFMA16(a, B2i[g][k], acc2[g]);
      }
      const f16x8* pA2 = (const f16x8*)&H2[prv][0];
      #pragma unroll
      for (int k = 0; k < 2; ++k){
        f16x8 a = pA2[4*k + quad];
        #pragma unroll
        for (int g = 0; g < 4; ++g)
          acc2[g] = MFMA16(a, B2h[g][k], acc2[g]);
      }
      if (l < 16){
        float gi = acc2[0][0], gf = acc2[1][0], gg = acc2[2][0], go = acc2[3][0];
        c2 = sigmoid_f(gf) * c2 + sigmoid_f(gi) * tanh_f(gg);
        float h = sigmoid_f(go) * tanh_f(c2);
        H2[cur][cellB] = (_Float16)h;
        if (st == TB - 1) out[b * EMB2 + cellB] = h;
      }
    }
    // no trailing barrier: all cross-phase hazards span a __syncthreads
    // (ping-pong buffers; see analysis)
  }
}

extern "C" void kernel_launch(void* const* d_in, const int* in_sizes, int n_in,
                              void* d_out, int out_size, void* d_ws, size_t ws_size,
                              hipStream_t stream) {
  lstm2_kernel<<<dim3(128), dim3(512), 0, stream>>>(
      (const float*)d_in[0],   // x
      (const float*)d_in[1],   // w_ih1
      (const float*)d_in[2],   // w_hh1
      (const float*)d_in[3],   // b_ih1
      (const float*)d_in[4],   // b_hh1
      (const float*)d_in[5],   // w_ih2
      (const float*)d_in[6],   // w_hh2
      (const float*)d_in[7],   // b_ih2
      (const float*)d_in[8],   // b_hh2
      (float*)d_out);
}

// Round 4
// 766.823 us; speedup vs baseline: 2.7999x; 1.0968x over previous
//
#include <hip/hip_runtime.h>

// 2-layer LSTM encoder, B=128, T=1024, F=1, HID=128, EMB=64.
// One WG (512 thr) per batch element; recurrent matvecs on the MFMA pipe
// (v_mfma_f32_16x16x32_f16, A = h broadcast via same-address LDS b128 reads).
// R4: software-pipelined layers — superstep s runs L1(s) on all waves and
// L2(s-1) on waves 0-3 concurrently (independent; both read h1(s-1)),
// ONE barrier per superstep. Ping-pong H1/H2; hazard audit:
//   h1: write slot s&1, reads slot (s-1)&1  -> all RAW/WAR span the barrier
//   h2: write slot (s-1)&1, read slot s&1   -> ditto
// No intra-superstep slot aliasing.

#define TB   1024
#define HID1 128
#define EMB2 64

typedef _Float16 f16x8 __attribute__((ext_vector_type(8)));
typedef float    f32x4 __attribute__((ext_vector_type(4)));

#define MFMA16(a,b,c) __builtin_amdgcn_mfma_f32_16x16x32_f16((a),(b),(c),0,0,0)

static __device__ __forceinline__ float fast_exp2(float x){
#if __has_builtin(__builtin_amdgcn_exp2f)
  return __builtin_amdgcn_exp2f(x);
#else
  return __exp2f(x);
#endif
}
static __device__ __forceinline__ float fast_rcp(float x){
#if __has_builtin(__builtin_amdgcn_rcpf)
  return __builtin_amdgcn_rcpf(x);
#else
  return 1.0f / x;
#endif
}
static __device__ __forceinline__ float sigmoid_f(float x){
  return fast_rcp(1.0f + fast_exp2(-1.44269504088896340736f * x));
}
static __device__ __forceinline__ float tanh_f(float x){
  return 1.0f - 2.0f * fast_rcp(1.0f + fast_exp2(2.88539008177792681472f * x));
}

static __device__ __forceinline__ f16x8 load_frag(const float* p){
  f16x8 r;
  #pragma unroll
  for (int j = 0; j < 8; ++j) r[j] = (_Float16)p[j];
  return r;
}

__launch_bounds__(512, 2)
__global__ void lstm2_kernel(const float* __restrict__ x,
                             const float* __restrict__ w_ih1,
                             const float* __restrict__ w_hh1,
                             const float* __restrict__ b_ih1,
                             const float* __restrict__ b_hh1,
                             const float* __restrict__ w_ih2,
                             const float* __restrict__ w_hh2,
                             const float* __restrict__ b_ih2,
                             const float* __restrict__ b_hh2,
                             float* __restrict__ out)
{
  __shared__ __align__(16) float    xs[TB];
  __shared__ __align__(16) _Float16 H1[2][HID1];  // h1 ping-pong
  __shared__ __align__(16) _Float16 H2[2][EMB2];  // h2 ping-pong

  const int t    = threadIdx.x;   // 0..511
  const int b    = blockIdx.x;    // 0..127
  const int l    = t & 63;        // lane
  const int w    = t >> 6;        // wave 0..7
  const int col  = l & 15;        // N-index within tile (cell)
  const int quad = l >> 4;        // k-quad 0..3

  // ---- layer-1 weight B-fragments: wave w owns N-tiles {w,w+8,w+16,w+24} ----
  f16x8 B1[4][4];
  float biasA[4], wxA[4];
  #pragma unroll
  for (int g = 0; g < 4; ++g){
    const int nA = (w + 8*g)*16 + col;
    biasA[g] = b_ih1[nA] + b_hh1[nA];
    wxA[g]   = w_ih1[nA];                       // w_ih1 is (512,1)
    #pragma unroll
    for (int k = 0; k < 4; ++k)
      B1[g][k] = load_frag(w_hh1 + nA*HID1 + k*32 + quad*8);
  }

  // ---- layer-2 weight B-fragments (waves 0-3): tiles {w,w+4,w+8,w+12} ----
  f16x8 B2i[4][4];   // w_ih2 part, K=128
  f16x8 B2h[4][2];   // w_hh2 part, K=64
  float biasB[4];
  if (w < 4){
    #pragma unroll
    for (int g = 0; g < 4; ++g){
      const int nB = (w + 4*g)*16 + col;
      biasB[g] = b_ih2[nB] + b_hh2[nB];
      #pragma unroll
      for (int k = 0; k < 4; ++k)
        B2i[g][k] = load_frag(w_ih2 + nB*HID1 + k*32 + quad*8);
      #pragma unroll
      for (int k = 0; k < 2; ++k)
        B2h[g][k] = load_frag(w_hh2 + nB*EMB2 + k*32 + quad*8);
    }
  }

  // ---- x preload + state init ----
  xs[t]       = x[b * TB + t];
  xs[t + 512] = x[b * TB + t + 512];
  if (t < HID1) { H1[0][t] = (_Float16)0.0f; H1[1][t] = (_Float16)0.0f; }
  else if (t < HID1 + EMB2){
    H2[0][t-HID1] = (_Float16)0.0f; H2[1][t-HID1] = (_Float16)0.0f;
  }
  __syncthreads();

  float c1 = 0.0f, c2 = 0.0f;
  const int cellA = 16*w + l;          // valid when l<16
  const int cellB = 16*w + l;          // valid when w<4 && l<16

#define LOAD_A1(slot, a)                                        \
  {                                                             \
    const f16x8* p_ = (const f16x8*)&H1[(slot)][0];             \
    _Pragma("unroll")                                           \
    for (int k_ = 0; k_ < 4; ++k_) (a)[k_] = p_[4*k_ + quad];   \
  }

#define PHASE_A(a1, s)                                          \
  {                                                             \
    const float xt_ = xs[(s)];                                  \
    f32x4 acc_[4];                                              \
    _Pragma("unroll")                                           \
    for (int g_ = 0; g_ < 4; ++g_){                             \
      const float pre_ = __builtin_fmaf(xt_, wxA[g_], biasA[g_]); \
      acc_[g_] = (f32x4){pre_, 0.0f, 0.0f, 0.0f};               \
    }                                                           \
    _Pragma("unroll")                                           \
    for (int k_ = 0; k_ < 4; ++k_){                             \
      _Pragma("unroll")                                         \
      for (int g_ = 0; g_ < 4; ++g_)                            \
        acc_[g_] = MFMA16((a1)[k_], B1[g_][k_], acc_[g_]);      \
    }                                                           \
    if (l < 16){                                                \
      float gi_ = acc_[0][0], gf_ = acc_[1][0];                 \
      float gg_ = acc_[2][0], go_ = acc_[3][0];                 \
      c1 = sigmoid_f(gf_) * c1 + sigmoid_f(gi_) * tanh_f(gg_);  \
      float h_ = sigmoid_f(go_) * tanh_f(c1);                   \
      H1[(s) & 1][cellA] = (_Float16)h_;                        \
    }                                                           \
  }

#define PHASE_B(a1, s2, store_out)                              \
  {                                                             \
    const f16x8* pA2_ = (const f16x8*)&H2[((s2) + 1) & 1][0];   \
    f16x8 a2_[2];                                               \
    _Pragma("unroll")                                           \
    for (int k_ = 0; k_ < 2; ++k_) a2_[k_] = pA2_[4*k_ + quad]; \
    f32x4 acc2_[4];                                             \
    _Pragma("unroll")                                           \
    for (int g_ = 0; g_ < 4; ++g_)                              \
      acc2_[g_] = (f32x4){biasB[g_], 0.0f, 0.0f, 0.0f};         \
    _Pragma("unroll")                                           \
    for (int k_ = 0; k_ < 4; ++k_){                             \
      _Pragma("unroll")                                         \
      for (int g_ = 0; g_ < 4; ++g_)                            \
        acc2_[g_] = MFMA16((a1)[k_], B2i[g_][k_], acc2_[g_]);   \
    }                                                           \
    _Pragma("unroll")                                           \
    for (int k_ = 0; k_ < 2; ++k_){                             \
      _Pragma("unroll")                                         \
      for (int g_ = 0; g_ < 4; ++g_)                            \
        acc2_[g_] = MFMA16(a2_[k_], B2h[g_][k_], acc2_[g_]);    \
    }                                                           \
    if (l < 16){                                                \
      float gi_ = acc2_[0][0], gf_ = acc2_[1][0];               \
      float gg_ = acc2_[2][0], go_ = acc2_[3][0];               \
      c2 = sigmoid_f(gf_) * c2 + sigmoid_f(gi_) * tanh_f(gg_);  \
      float h_ = sigmoid_f(go_) * tanh_f(c2);                   \
      if (store_out) out[b * EMB2 + cellB] = h_;                \
      else           H2[(s2) & 1][cellB] = (_Float16)h_;        \
    }                                                           \
  }

  // ---- prologue: L1 step 0 (h1(-1) = zeros in slot 1) ----
  {
    f16x8 a1[4];
    LOAD_A1(1, a1);
    PHASE_A(a1, 0);
  }
  __syncthreads();

  // ---- main pipelined loop: superstep s = L1(s) || L2(s-1), one barrier ----
  #pragma unroll 1
  for (int s = 1; s < TB; ++s){
    f16x8 a1[4];
    LOAD_A1((s + 1) & 1, a1);      // h1(s-1), shared by both phases
    PHASE_A(a1, s);
    if (w < 4){
      PHASE_B(a1, s - 1, false);
    }
    __syncthreads();
  }

  // ---- epilogue: L2 step TB-1 -> output ----
  if (w < 4){
    f16x8 a1[4];
    LOAD_A1((TB - 1) & 1, a1);     // h1(TB-1)
    PHASE_B(a1, TB - 1, true);
  }

#undef LOAD_A1
#undef PHASE_A
#undef PHASE_B
}

extern "C" void kernel_launch(void* const* d_in, const int* in_sizes, int n_in,
                              void* d_out, int out_size, void* d_ws, size_t ws_size,
                              hipStream_t stream) {
  lstm2_kernel<<<dim3(128), dim3(512), 0, stream>>>(
      (const float*)d_in[0],   // x
      (const float*)d_in[1],   // w_ih1
      (const float*)d_in[2],   // w_hh1
      (const float*)d_in[3],   // b_ih1
      (const float*)d_in[4],   // b_hh1
      (const float*)d_in[5],   // w_ih2
      (const float*)d_in[6],   // w_hh2
      (const float*)d_in[7],   // b_ih2
      (const float*)d_in[8],   // b_hh2
      (float*)d_out);
}